// Round 2
// baseline (308.506 us; speedup 1.0000x reference)
//
#include <hip/hip_runtime.h>

// j = 1 - log10(1024*|x-y| + 1), elementwise over float32 tensors.
// shape (8,16,4096,64) = 33,554,432 f32 elements per tensor (134.2 MB each).
//
// R2/R3 theory: inputs (268 MB) nearly fit the 256 MiB Infinity Cache and stay
// warm across iterations (measured FETCH = 134 MB == half the input reads,
// i.e. ~50% L3 hit). The 134 MB output stream write-allocates through the
// cache hierarchy and is what evicts the other half. Output is never re-read
// -> store it non-temporally so the input set stays L3-resident.
// Prediction: FETCH_SIZE 131 MB -> <60 MB, dispatch 105 -> ~60-80 us.
//
// R3 fix: __builtin_nontemporal_store requires a NATIVE clang vector type,
// not HIP's float4 class. Use ext_vector_type(4).

typedef float f32x4 __attribute__((ext_vector_type(4)));

__device__ __forceinline__ float j_elem(float xv, float yv) {
    float d = xv - yv;
    // sqrt(1024^2 * d^2) == 1024 * |d|
    float dist = 1024.0f * fabsf(d);
    // log10(v) = log2(v) * log10(2); v_log_f32 accuracy ~1 ulp, threshold 5.75e-2
    return 1.0f - 0.30102999566398120f * __log2f(dist + 1.0f);
}

__global__ __launch_bounds__(256) void j_vec4_nt_kernel(const f32x4* __restrict__ x,
                                                        const f32x4* __restrict__ y,
                                                        f32x4* __restrict__ out,
                                                        int nvec) {
    int i = blockIdx.x * blockDim.x + threadIdx.x;
    if (i >= nvec) return;
    f32x4 xv = x[i];
    f32x4 yv = y[i];
    f32x4 ov;
    ov.x = j_elem(xv.x, yv.x);
    ov.y = j_elem(xv.y, yv.y);
    ov.z = j_elem(xv.z, yv.z);
    ov.w = j_elem(xv.w, yv.w);
    // Non-temporal store: output is write-once, never re-read. Keeps the
    // 134 MB write stream from evicting the L3-resident input tensors.
    __builtin_nontemporal_store(ov, &out[i]);
}

__global__ __launch_bounds__(256) void j_tail_kernel(const float* __restrict__ x,
                                                     const float* __restrict__ y,
                                                     float* __restrict__ out,
                                                     int start, int n) {
    int i = start + blockIdx.x * blockDim.x + threadIdx.x;
    if (i >= n) return;
    float v = j_elem(x[i], y[i]);
    __builtin_nontemporal_store(v, &out[i]);
}

extern "C" void kernel_launch(void* const* d_in, const int* in_sizes, int n_in,
                              void* d_out, int out_size, void* d_ws, size_t ws_size,
                              hipStream_t stream) {
    const int n = out_size;                  // 33,554,432 f32 elements
    const int nvec = n / 4;                  // 4 f32 per float4
    const int rem = n - nvec * 4;

    if (nvec > 0) {
        int blocks = (nvec + 255) / 256;
        j_vec4_nt_kernel<<<blocks, 256, 0, stream>>>(
            (const f32x4*)d_in[0], (const f32x4*)d_in[1], (f32x4*)d_out, nvec);
    }
    if (rem > 0) {
        j_tail_kernel<<<1, 256, 0, stream>>>(
            (const float*)d_in[0], (const float*)d_in[1],
            (float*)d_out, nvec * 4, n);
    }
}